// Round 12
// baseline (896.617 us; speedup 1.0000x reference)
//
#include <hip/hip_runtime.h>
#include <hip/hip_cooperative_groups.h>
#include <math.h>

namespace cg = cooperative_groups;

#define NN 20000
#define NN_PAD 20096   // NN rounded up to TM; pad rows are garbage, never stored
#define EE 320000
#define RR 3
#define LL 3
#define HH 4
#define DD 64
#define CDIM 256   // H*D == IN
#define OUTD 128
#define NEG 0.2f

typedef float f32x4 __attribute__((ext_vector_type(4)));
typedef short sh8 __attribute__((ext_vector_type(8)));

__device__ __forceinline__ ushort f2bf(float f) {
    union { float f; uint u; } v; v.f = f;
    uint r = (v.u + 0x7FFF + ((v.u >> 16) & 1)) >> 16;   // RNE
    return (ushort)r;
}
__device__ __forceinline__ float bf2f(ushort u) {
    union { uint u; float f; } v; v.u = ((uint)u) << 16;
    return v.f;
}
__device__ __forceinline__ float bflo(uint p) { return bf2f((ushort)(p & 0xffff)); }
__device__ __forceinline__ float bfhi(uint p) { return bf2f((ushort)(p >> 16)); }

// async global->LDS, 16 B per lane; LDS dst is wave-uniform base + lane*16
__device__ __forceinline__ void glds16(const ushort* g, ushort* l) {
    __builtin_amdgcn_global_load_lds(
        (const __attribute__((address_space(1))) void*)g,
        (__attribute__((address_space(3))) void*)l, 16, 0, 0);
}

// ---------------- cooperative build kernel ----------------
// One launch replaces: memset(deg), cvt_bf16x4, prep_all, count_deg,
// scan_kernel, fill_csr (6 dispatches -> 1, removing 5 launch gaps and the
// near-idle 3-CU scan dispatch). 3 grid-wide syncs.

__global__ __launch_bounds__(256) void build_all(
    const float* __restrict__ x, const float* __restrict__ W,
    const float* __restrict__ fc_w,
    const int* __restrict__ edge_src, const int* __restrict__ edge_dst,
    ushort* __restrict__ x16, ushort* __restrict__ Wt, ushort* __restrict__ fct,
    int* __restrict__ deg, int* __restrict__ row_ptr,
    int* __restrict__ cursor, int* __restrict__ csr_src) {
    cg::grid_group grid = cg::this_grid();
    int nb = gridDim.x, bid = blockIdx.x, t = threadIdx.x;
    int gid = bid * 256 + t, gsz = nb * 256;
    __shared__ float tile[32][33];
    __shared__ int wsum[4];

    // Phase A: zero deg + x fp32->bf16 + weight transpose/convert
    for (int i = gid; i < RR * NN; i += gsz) deg[i] = 0;
    for (int i = gid; i < NN * CDIM / 4; i += gsz) {
        float4 v = *(const float4*)(x + (size_t)i * 4);
        ushort4 o;
        o.x = f2bf(v.x); o.y = f2bf(v.y); o.z = f2bf(v.z); o.w = f2bf(v.w);
        *(ushort4*)(x16 + (size_t)i * 4) = o;
    }
    {
        int tjobs = LL * RR * 64 + (CDIM / 32) * (OUTD / 32);   // 576 + 32
        int tx = t & 31, ty = t >> 5;
        for (int job = bid; job < tjobs; job += nb) {
            const float* src; ushort* dst; int N, kb, nbv;
            if (job < LL * RR * 64) {
                int z = job >> 6, tj = job & 63;
                src = W + (size_t)z * CDIM * CDIM;
                dst = Wt + (size_t)z * CDIM * CDIM;
                N = CDIM; kb = (tj >> 3) * 32; nbv = (tj & 7) * 32;
            } else {
                int tj = job - LL * RR * 64;
                src = fc_w; dst = fct; N = OUTD;
                kb = (tj >> 2) * 32; nbv = (tj & 3) * 32;
            }
            __syncthreads();   // protect tile reuse across jobs
            for (int yy = ty; yy < 32; yy += 8)
                tile[yy][tx] = src[(size_t)(kb + yy) * N + nbv + tx];
            __syncthreads();
            for (int yy = ty; yy < 32; yy += 8)
                dst[(size_t)(nbv + yy) * CDIM + kb + tx] = f2bf(tile[tx][yy]);
        }
    }
    grid.sync();

    // Phase B: degree count
    for (int i = gid; i < RR * EE; i += gsz) {
        int r = i / EE;
        atomicAdd(&deg[r * NN + edge_dst[i]], 1);
    }
    grid.sync();

    // Phase C: exclusive scan -> row_ptr + cursor (blocks 0..RR-1 only)
    if (bid < RR) {
        int r = bid;
        const int* d = deg + r * NN;
        int* rp = row_ptr + r * (NN + 1);
        int* cur = cursor + r * (NN + 1);
        int lane = t & 63, wv = t >> 6;
        if (t == 0) { rp[0] = 0; cur[0] = 0; }
        int carry = 0;
        for (int base = 0; base < NN; base += 256) {
            int i = base + t;
            int v = (i < NN) ? d[i] : 0;
            int s = v;
            #pragma unroll
            for (int off2 = 1; off2 < 64; off2 <<= 1) {
                int n = __shfl_up(s, off2, 64);
                if (lane >= off2) s += n;
            }
            if (lane == 63) wsum[wv] = s;
            __syncthreads();
            int wadd = 0;
            for (int w = 0; w < wv; w++) wadd += wsum[w];
            int incl = carry + wadd + s;
            if (i < NN) { rp[i + 1] = incl; cur[i + 1] = incl; }
            carry += wsum[0] + wsum[1] + wsum[2] + wsum[3];
            __syncthreads();
        }
    }
    grid.sync();

    // Phase D: CSR fill (cursor = copy of row_ptr, bumped atomically)
    for (int i = gid; i < RR * EE; i += gsz) {
        int r = i / EE;
        int dst = edge_dst[i];
        int pos = atomicAdd(&cursor[r * (NN + 1) + dst], 1);
        csr_src[r * EE + pos] = edge_src[i];
    }
}

// ---------------- bf16 MFMA GEMM (+ fused el/er epilogue) — r8-proven ----------

#define TM 128
#define TN 128
#define TK 32

__global__ __launch_bounds__(256) void gemm_bf16(
    const ushort* __restrict__ A, const ushort* __restrict__ Bt0, void* __restrict__ C0,
    int M, int K, int Ncol, long strideB, long strideC,
    const float* __restrict__ bias, int out_fp32,
    const float* __restrict__ al_all, const float* __restrict__ ar_all,
    float* __restrict__ el_all, float* __restrict__ er_all) {
    __shared__ alignas(16) ushort As[TM * 32];
    __shared__ alignas(16) ushort Bs[TN * 32];
    const ushort* Bt = Bt0 + (size_t)blockIdx.z * strideB;
    int m0 = blockIdx.x * TM, n0 = blockIdx.y * TN;
    int t = threadIdx.x;
    int wave = t >> 6, lane = t & 63;
    int q = lane >> 4, l16 = lane & 15;
    int wrow = (wave >> 1) * 64, wcol = (wave & 1) * 64;

    int sw = (q ^ ((l16 >> 1) & 3)) * 8;
    int a_off[4], b_off[4];
    #pragma unroll
    for (int i = 0; i < 4; i++) {
        a_off[i] = (wrow + i * 16 + l16) * 32 + sw;
        b_off[i] = (wcol + i * 16 + l16) * 32 + sw;
    }
    int row_a = t >> 2;
    int ch_a  = ((t & 3) ^ ((row_a >> 1) & 3)) * 8;

    f32x4 acc[4][4];
    #pragma unroll
    for (int i = 0; i < 4; i++)
        #pragma unroll
        for (int j = 0; j < 4; j++)
            #pragma unroll
            for (int k = 0; k < 4; k++) acc[i][j][k] = 0.f;

    for (int k0 = 0; k0 < K; k0 += TK) {
        #pragma unroll
        for (int s = 0; s < 2; s++) {
            int qid = t + s * 256;
            int row = row_a + s * 64;
            glds16(A + (size_t)(m0 + row) * K + k0 + ch_a, As + qid * 8);
        }
        #pragma unroll
        for (int s = 0; s < 2; s++) {
            int qid = t + s * 256;
            int row = row_a + s * 64;
            glds16(Bt + (size_t)(n0 + row) * K + k0 + ch_a, Bs + qid * 8);
        }
        __syncthreads();
        sh8 af[4], bfr[4];
        #pragma unroll
        for (int i = 0; i < 4; i++) af[i] = *(const sh8*)(As + a_off[i]);
        #pragma unroll
        for (int j = 0; j < 4; j++) bfr[j] = *(const sh8*)(Bs + b_off[j]);
        #pragma unroll
        for (int i = 0; i < 4; i++)
            #pragma unroll
            for (int j = 0; j < 4; j++)
                acc[i][j] = __builtin_amdgcn_mfma_f32_16x16x32_bf16(af[i], bfr[j], acc[i][j], 0, 0, 0);
        __syncthreads();
    }

    if (out_fp32) {
        float* C = (float*)C0 + (size_t)blockIdx.z * strideC;
        #pragma unroll
        for (int i = 0; i < 4; i++) {
            #pragma unroll
            for (int reg = 0; reg < 4; reg++) {
                int row = m0 + wrow + i * 16 + q * 4 + reg;
                if (row >= M) continue;
                #pragma unroll
                for (int j = 0; j < 4; j++) {
                    int col = n0 + wcol + j * 16 + l16;
                    float v = acc[i][j][reg];
                    if (bias) v += bias[col];
                    C[(size_t)row * Ncol + col] = v;
                }
            }
        }
    } else {
        ushort* C = (ushort*)C0 + (size_t)blockIdx.z * strideC;
        #pragma unroll
        for (int i = 0; i < 4; i++) {
            #pragma unroll
            for (int reg = 0; reg < 4; reg++) {
                int row = m0 + wrow + i * 16 + q * 4 + reg;
                if (row >= M) continue;
                #pragma unroll
                for (int j = 0; j < 4; j++) {
                    int col = n0 + wcol + j * 16 + l16;
                    C[(size_t)row * Ncol + col] = f2bf(acc[i][j][reg]);
                }
            }
        }
    }

    if (el_all) {
        const float* al = al_all + (size_t)blockIdx.z * CDIM;
        const float* ar = ar_all + (size_t)blockIdx.z * CDIM;
        float* elp = el_all + (size_t)blockIdx.z * NN * HH;
        float* erp = er_all + (size_t)blockIdx.z * NN * HH;
        int head = (n0 + wcol) >> 6;
        float alj[4], arj[4];
        #pragma unroll
        for (int j = 0; j < 4; j++) {
            int gcol = n0 + wcol + j * 16 + l16;
            alj[j] = al[gcol];
            arj[j] = ar[gcol];
        }
        #pragma unroll
        for (int i = 0; i < 4; i++) {
            #pragma unroll
            for (int reg = 0; reg < 4; reg++) {
                int row = m0 + wrow + i * 16 + q * 4 + reg;
                float pl = 0.f, pr = 0.f;
                #pragma unroll
                for (int j = 0; j < 4; j++) {
                    pl = fmaf(acc[i][j][reg], alj[j], pl);
                    pr = fmaf(acc[i][j][reg], arj[j], pr);
                }
                #pragma unroll
                for (int m = 1; m < 16; m <<= 1) {
                    pl += __shfl_xor(pl, m, 64);
                    pr += __shfl_xor(pr, m, 64);
                }
                if (l16 == 0 && row < M) {
                    elp[(size_t)row * HH + head] = pl;
                    erp[(size_t)row * HH + head] = pr;
                }
            }
        }
    }
}

// ---------------- fused softmax + aggregation (r4-proven config, frozen) ----------
// Sits on the ~3.2 TB/s L2-miss-path plateau (6.7 TB/s logical); lives off
// occupancy (VGPR 36, ~58%). Do not touch (r5/r6 regressions documented).
__global__ __launch_bounds__(256) void aggregate_fused(
    const ushort* __restrict__ feat16, const float* __restrict__ el,
    const float* __restrict__ er, const int* __restrict__ row_ptr,
    const int* __restrict__ csr_src, const float* __restrict__ bias,
    ushort* __restrict__ hout, int relu) {
    int wv = threadIdx.x >> 6, lane = threadIdx.x & 63;
    int node = blockIdx.x * 4 + wv;
    if (node >= NN) return;
    int c0 = lane * 4;
    int h = lane >> 4;
    float t0 = 0.f, t1 = 0.f, t2 = 0.f, t3 = 0.f;
    #pragma unroll
    for (int r = 0; r < RR; r++) {
        const int* rp = row_ptr + r * (NN + 1);
        int beg = rp[node], end = rp[node + 1];
        const ushort* fr = feat16 + (size_t)r * NN * CDIM;
        const float* elr = el + (size_t)r * NN * HH;
        float ern = er[((size_t)r * NN + node) * HH + h];
        const int* cs = csr_src + (size_t)r * EE;
        float p0 = 0.f, p1 = 0.f, p2 = 0.f, p3 = 0.f, ssum = 0.f;
        int e = beg;
        for (; e + 4 <= end; e += 4) {
            int s0 = cs[e], s1 = cs[e + 1], s2 = cs[e + 2], s3 = cs[e + 3];
            float x0 = elr[s0 * HH + h];
            float x1 = elr[s1 * HH + h];
            float x2 = elr[s2 * HH + h];
            float x3 = elr[s3 * HH + h];
            uint2 f0 = *(const uint2*)(fr + (size_t)s0 * CDIM + c0);
            uint2 f1 = *(const uint2*)(fr + (size_t)s1 * CDIM + c0);
            uint2 f2 = *(const uint2*)(fr + (size_t)s2 * CDIM + c0);
            uint2 f3 = *(const uint2*)(fr + (size_t)s3 * CDIM + c0);
            x0 += ern; x1 += ern; x2 += ern; x3 += ern;
            x0 = x0 > 0.f ? x0 : NEG * x0;
            x1 = x1 > 0.f ? x1 : NEG * x1;
            x2 = x2 > 0.f ? x2 : NEG * x2;
            x3 = x3 > 0.f ? x3 : NEG * x3;
            float a0 = __expf(x0), a1 = __expf(x1), a2 = __expf(x2), a3 = __expf(x3);
            ssum += a0 + a1 + a2 + a3;
            p0 = fmaf(a0, bflo(f0.x), p0); p1 = fmaf(a0, bfhi(f0.x), p1);
            p2 = fmaf(a0, bflo(f0.y), p2); p3 = fmaf(a0, bfhi(f0.y), p3);
            p0 = fmaf(a1, bflo(f1.x), p0); p1 = fmaf(a1, bfhi(f1.x), p1);
            p2 = fmaf(a1, bflo(f1.y), p2); p3 = fmaf(a1, bfhi(f1.y), p3);
            p0 = fmaf(a2, bflo(f2.x), p0); p1 = fmaf(a2, bfhi(f2.x), p1);
            p2 = fmaf(a2, bflo(f2.y), p2); p3 = fmaf(a2, bfhi(f2.y), p3);
            p0 = fmaf(a3, bflo(f3.x), p0); p1 = fmaf(a3, bfhi(f3.x), p1);
            p2 = fmaf(a3, bflo(f3.y), p2); p3 = fmaf(a3, bfhi(f3.y), p3);
        }
        for (; e < end; e++) {
            int s = cs[e];
            float x = elr[s * HH + h] + ern;
            x = x > 0.f ? x : NEG * x;
            float a = __expf(x);
            uint2 f = *(const uint2*)(fr + (size_t)s * CDIM + c0);
            ssum += a;
            p0 = fmaf(a, bflo(f.x), p0); p1 = fmaf(a, bfhi(f.x), p1);
            p2 = fmaf(a, bflo(f.y), p2); p3 = fmaf(a, bfhi(f.y), p3);
        }
        float is = (end > beg) ? 1.f / ssum : 0.f;
        t0 += p0 * is + bias[r * CDIM + c0];
        t1 += p1 * is + bias[r * CDIM + c0 + 1];
        t2 += p2 * is + bias[r * CDIM + c0 + 2];
        t3 += p3 * is + bias[r * CDIM + c0 + 3];
    }
    if (relu) {
        t0 = fmaxf(t0, 0.f); t1 = fmaxf(t1, 0.f);
        t2 = fmaxf(t2, 0.f); t3 = fmaxf(t3, 0.f);
    }
    uint2 o;
    o.x = (uint)f2bf(t0) | ((uint)f2bf(t1) << 16);
    o.y = (uint)f2bf(t2) | ((uint)f2bf(t3) << 16);
    *(uint2*)(hout + (size_t)node * CDIM + c0) = o;
}

// ---------------- launcher ----------------

extern "C" void kernel_launch(void* const* d_in, const int* in_sizes, int n_in,
                              void* d_out, int out_size, void* d_ws, size_t ws_size,
                              hipStream_t stream) {
    const float* x        = (const float*)d_in[0];
    const int*   edge_src = (const int*)d_in[1];
    const int*   edge_dst = (const int*)d_in[2];
    const float* W        = (const float*)d_in[3];
    const float* attn_l   = (const float*)d_in[4];
    const float* attn_r   = (const float*)d_in[5];
    const float* bias     = (const float*)d_in[6];
    const float* fc_w     = (const float*)d_in[7];
    const float* fc_b     = (const float*)d_in[8];
    float* out = (float*)d_out;

    char* ws = (char*)d_ws;
    size_t off = 0;
    auto alloc = [&](size_t bytes) {
        void* p = ws + off;
        off = (off + bytes + 255) & ~(size_t)255;
        return p;
    };
    ushort* x16    = (ushort*)alloc((size_t)NN_PAD * CDIM * 2);  // padded: glds A-source
    ushort* h16    = (ushort*)alloc((size_t)NN_PAD * CDIM * 2);  // padded: glds A-source
    ushort* feat16 = (ushort*)alloc((size_t)RR * NN * CDIM * 2);
    ushort* Wt16   = (ushort*)alloc((size_t)LL * RR * CDIM * CDIM * 2);
    ushort* fct16  = (ushort*)alloc((size_t)OUTD * CDIM * 2);
    float* el      = (float*)alloc((size_t)RR * NN * HH * 4);
    float* er      = (float*)alloc((size_t)RR * NN * HH * 4);
    int* row_ptr   = (int*)alloc((size_t)RR * (NN + 1) * 4);
    int* cursor    = (int*)alloc((size_t)RR * (NN + 1) * 4);
    int* csr_src   = (int*)alloc((size_t)RR * EE * 4);
    int* deg       = (int*)alloc((size_t)RR * NN * 4);

    // one cooperative launch: zero+cvt+transpose | count | scan | fill
    {
        void* args[] = {
            (void*)&x, (void*)&W, (void*)&fc_w,
            (void*)&edge_src, (void*)&edge_dst,
            (void*)&x16, (void*)&Wt16, (void*)&fct16,
            (void*)&deg, (void*)&row_ptr, (void*)&cursor, (void*)&csr_src
        };
        hipLaunchCooperativeKernel((const void*)build_all, dim3(1024), dim3(256),
                                   args, 0, stream);
    }

    const ushort* hin = x16;
    for (int l = 0; l < LL; l++) {
        const ushort* Wl = Wt16 + (size_t)l * RR * CDIM * CDIM;
        dim3 g(NN_PAD / TM, CDIM / TN, RR);
        gemm_bf16<<<g, dim3(256), 0, stream>>>(hin, Wl, feat16, NN, CDIM, CDIM,
                                               (long)CDIM * CDIM, (long)NN * CDIM, nullptr, 0,
                                               attn_l + (size_t)l * RR * CDIM,
                                               attn_r + (size_t)l * RR * CDIM, el, er);
        aggregate_fused<<<dim3(NN / 4), dim3(256), 0, stream>>>(
            feat16, el, er, row_ptr, csr_src, bias + (size_t)l * RR * CDIM,
            h16, (l != LL - 1) ? 1 : 0);
        hin = h16;
    }
    dim3 gf(NN_PAD / TM, OUTD / TN, 1);
    gemm_bf16<<<gf, dim3(256), 0, stream>>>(h16, fct16, out, NN, CDIM, OUTD,
                                            0, 0, fc_b, 1, nullptr, nullptr, nullptr, nullptr);
}

// Round 13
// 517.082 us; speedup vs baseline: 1.7340x; 1.7340x over previous
//
#include <hip/hip_runtime.h>
#include <math.h>

#define NN 20000
#define NN_PAD 20096   // NN rounded up to TM; pad rows are garbage, never stored
#define EE 320000
#define RR 3
#define LL 3
#define HH 4
#define DD 64
#define CDIM 256   // H*D == IN
#define OUTD 128
#define NEG 0.2f

typedef float f32x4 __attribute__((ext_vector_type(4)));
typedef short sh8 __attribute__((ext_vector_type(8)));

__device__ __forceinline__ ushort f2bf(float f) {
    union { float f; uint u; } v; v.f = f;
    uint r = (v.u + 0x7FFF + ((v.u >> 16) & 1)) >> 16;   // RNE
    return (ushort)r;
}
__device__ __forceinline__ float bf2f(ushort u) {
    union { uint u; float f; } v; v.u = ((uint)u) << 16;
    return v.f;
}
__device__ __forceinline__ float bflo(uint p) { return bf2f((ushort)(p & 0xffff)); }
__device__ __forceinline__ float bfhi(uint p) { return bf2f((ushort)(p >> 16)); }

// async global->LDS, 16 B per lane; LDS dst is wave-uniform base + lane*16
__device__ __forceinline__ void glds16(const ushort* g, ushort* l) {
    __builtin_amdgcn_global_load_lds(
        (const __attribute__((address_space(1))) void*)g,
        (__attribute__((address_space(3))) void*)l, 16, 0, 0);
}

// ---------------- fused prep: cvt + weight transpose + degree count --------------
// The three jobs are mutually independent -> no internal sync needed (r12's
// cooperative grid.sync cost ~150us each on 8 XCDs; never again). Block-range
// partition: [0,104) cvt, [104,712) transpose tiles, [712,1352) count_deg.
// memset(deg) precedes in stream order.

#define PREP_CVT 104
#define PREP_TRN 608   // LL*RR*64 + 32 tile jobs
#define PREP_CNT 640
#define PREP_NB (PREP_CVT + PREP_TRN + PREP_CNT)

__global__ __launch_bounds__(256) void prep_fused(
    const float* __restrict__ x, const float* __restrict__ W,
    const float* __restrict__ fc_w, const int* __restrict__ edge_dst,
    ushort* __restrict__ x16, ushort* __restrict__ Wt, ushort* __restrict__ fct,
    int* __restrict__ deg) {
    int bid = blockIdx.x, t = threadIdx.x;
    if (bid < PREP_CVT) {
        // x fp32 -> bf16: 1.28M elems / 4 per thread
        int n4 = NN * CDIM / 4;
        for (int i = bid * 256 + t; i < n4; i += PREP_CVT * 256) {
            float4 v = *(const float4*)(x + (size_t)i * 4);
            ushort4 o;
            o.x = f2bf(v.x); o.y = f2bf(v.y); o.z = f2bf(v.z); o.w = f2bf(v.w);
            *(ushort4*)(x16 + (size_t)i * 4) = o;
        }
    } else if (bid < PREP_CVT + PREP_TRN) {
        // one 32x32 transpose tile per block
        __shared__ float tile[32][33];
        int job = bid - PREP_CVT;
        const float* src; ushort* dst; int N, kb, nbv;
        if (job < LL * RR * 64) {
            int z = job >> 6, tj = job & 63;
            src = W + (size_t)z * CDIM * CDIM;
            dst = Wt + (size_t)z * CDIM * CDIM;
            N = CDIM; kb = (tj >> 3) * 32; nbv = (tj & 7) * 32;
        } else {
            int tj = job - LL * RR * 64;
            src = fc_w; dst = fct; N = OUTD;
            kb = (tj >> 2) * 32; nbv = (tj & 3) * 32;
        }
        int tx = t & 31, ty = t >> 5;
        for (int yy = ty; yy < 32; yy += 8)
            tile[yy][tx] = src[(size_t)(kb + yy) * N + nbv + tx];
        __syncthreads();
        for (int yy = ty; yy < 32; yy += 8)
            dst[(size_t)(nbv + yy) * CDIM + kb + tx] = f2bf(tile[tx][yy]);
    } else {
        int b = bid - PREP_CVT - PREP_TRN;
        for (int i = b * 256 + t; i < RR * EE; i += PREP_CNT * 256) {
            int r = i / EE;
            atomicAdd(&deg[r * NN + edge_dst[i]], 1);
        }
    }
}

// one block per relation; wave-shfl scan; writes row_ptr AND cursor copy.
__global__ __launch_bounds__(1024) void scan_kernel(
    const int* __restrict__ deg, int* __restrict__ row_ptr, int* __restrict__ cursor) {
    int r = blockIdx.x;
    const int* d = deg + r * NN;
    int* rp = row_ptr + r * (NN + 1);
    int* cur = cursor + r * (NN + 1);
    __shared__ int wsum[16];
    int lane = threadIdx.x & 63, wv = threadIdx.x >> 6;
    if (threadIdx.x == 0) { rp[0] = 0; cur[0] = 0; }
    int carry = 0;
    for (int base = 0; base < NN; base += 1024) {
        int i = base + threadIdx.x;
        int v = (i < NN) ? d[i] : 0;
        int s = v;
        #pragma unroll
        for (int off = 1; off < 64; off <<= 1) {
            int n = __shfl_up(s, off, 64);
            if (lane >= off) s += n;
        }
        if (lane == 63) wsum[wv] = s;
        __syncthreads();
        if (wv == 0) {
            int ws = (lane < 16) ? wsum[lane] : 0;
            #pragma unroll
            for (int off = 1; off < 16; off <<= 1) {
                int n = __shfl_up(ws, off, 64);
                if (lane >= off) ws += n;
            }
            if (lane < 16) wsum[lane] = ws;
        }
        __syncthreads();
        int incl = carry + (wv ? wsum[wv - 1] : 0) + s;
        if (i < NN) { rp[i + 1] = incl; cur[i + 1] = incl; }
        carry += wsum[15];
        __syncthreads();
    }
}

__global__ void fill_csr(const int* __restrict__ edge_src, const int* __restrict__ edge_dst,
                         int* __restrict__ cursor, int* __restrict__ csr_src) {
    int i = blockIdx.x * blockDim.x + threadIdx.x;
    if (i >= RR * EE) return;
    int r = i / EE;
    int dst = edge_dst[i];
    int pos = atomicAdd(&cursor[r * (NN + 1) + dst], 1);
    csr_src[r * EE + pos] = edge_src[i];
}

// ---------------- bf16 MFMA GEMM (+ fused el/er epilogue) — r8-proven ----------

#define TM 128
#define TN 128
#define TK 32

__global__ __launch_bounds__(256) void gemm_bf16(
    const ushort* __restrict__ A, const ushort* __restrict__ Bt0, void* __restrict__ C0,
    int M, int K, int Ncol, long strideB, long strideC,
    const float* __restrict__ bias, int out_fp32,
    const float* __restrict__ al_all, const float* __restrict__ ar_all,
    float* __restrict__ el_all, float* __restrict__ er_all) {
    __shared__ alignas(16) ushort As[TM * 32];
    __shared__ alignas(16) ushort Bs[TN * 32];
    const ushort* Bt = Bt0 + (size_t)blockIdx.z * strideB;
    int m0 = blockIdx.x * TM, n0 = blockIdx.y * TN;
    int t = threadIdx.x;
    int wave = t >> 6, lane = t & 63;
    int q = lane >> 4, l16 = lane & 15;
    int wrow = (wave >> 1) * 64, wcol = (wave & 1) * 64;

    int sw = (q ^ ((l16 >> 1) & 3)) * 8;
    int a_off[4], b_off[4];
    #pragma unroll
    for (int i = 0; i < 4; i++) {
        a_off[i] = (wrow + i * 16 + l16) * 32 + sw;
        b_off[i] = (wcol + i * 16 + l16) * 32 + sw;
    }
    int row_a = t >> 2;
    int ch_a  = ((t & 3) ^ ((row_a >> 1) & 3)) * 8;

    f32x4 acc[4][4];
    #pragma unroll
    for (int i = 0; i < 4; i++)
        #pragma unroll
        for (int j = 0; j < 4; j++)
            #pragma unroll
            for (int k = 0; k < 4; k++) acc[i][j][k] = 0.f;

    for (int k0 = 0; k0 < K; k0 += TK) {
        #pragma unroll
        for (int s = 0; s < 2; s++) {
            int qid = t + s * 256;
            int row = row_a + s * 64;
            glds16(A + (size_t)(m0 + row) * K + k0 + ch_a, As + qid * 8);
        }
        #pragma unroll
        for (int s = 0; s < 2; s++) {
            int qid = t + s * 256;
            int row = row_a + s * 64;
            glds16(Bt + (size_t)(n0 + row) * K + k0 + ch_a, Bs + qid * 8);
        }
        __syncthreads();
        sh8 af[4], bfr[4];
        #pragma unroll
        for (int i = 0; i < 4; i++) af[i] = *(const sh8*)(As + a_off[i]);
        #pragma unroll
        for (int j = 0; j < 4; j++) bfr[j] = *(const sh8*)(Bs + b_off[j]);
        #pragma unroll
        for (int i = 0; i < 4; i++)
            #pragma unroll
            for (int j = 0; j < 4; j++)
                acc[i][j] = __builtin_amdgcn_mfma_f32_16x16x32_bf16(af[i], bfr[j], acc[i][j], 0, 0, 0);
        __syncthreads();
    }

    if (out_fp32) {
        float* C = (float*)C0 + (size_t)blockIdx.z * strideC;
        #pragma unroll
        for (int i = 0; i < 4; i++) {
            #pragma unroll
            for (int reg = 0; reg < 4; reg++) {
                int row = m0 + wrow + i * 16 + q * 4 + reg;
                if (row >= M) continue;
                #pragma unroll
                for (int j = 0; j < 4; j++) {
                    int col = n0 + wcol + j * 16 + l16;
                    float v = acc[i][j][reg];
                    if (bias) v += bias[col];
                    C[(size_t)row * Ncol + col] = v;
                }
            }
        }
    } else {
        ushort* C = (ushort*)C0 + (size_t)blockIdx.z * strideC;
        #pragma unroll
        for (int i = 0; i < 4; i++) {
            #pragma unroll
            for (int reg = 0; reg < 4; reg++) {
                int row = m0 + wrow + i * 16 + q * 4 + reg;
                if (row >= M) continue;
                #pragma unroll
                for (int j = 0; j < 4; j++) {
                    int col = n0 + wcol + j * 16 + l16;
                    C[(size_t)row * Ncol + col] = f2bf(acc[i][j][reg]);
                }
            }
        }
    }

    if (el_all) {
        const float* al = al_all + (size_t)blockIdx.z * CDIM;
        const float* ar = ar_all + (size_t)blockIdx.z * CDIM;
        float* elp = el_all + (size_t)blockIdx.z * NN * HH;
        float* erp = er_all + (size_t)blockIdx.z * NN * HH;
        int head = (n0 + wcol) >> 6;
        float alj[4], arj[4];
        #pragma unroll
        for (int j = 0; j < 4; j++) {
            int gcol = n0 + wcol + j * 16 + l16;
            alj[j] = al[gcol];
            arj[j] = ar[gcol];
        }
        #pragma unroll
        for (int i = 0; i < 4; i++) {
            #pragma unroll
            for (int reg = 0; reg < 4; reg++) {
                int row = m0 + wrow + i * 16 + q * 4 + reg;
                float pl = 0.f, pr = 0.f;
                #pragma unroll
                for (int j = 0; j < 4; j++) {
                    pl = fmaf(acc[i][j][reg], alj[j], pl);
                    pr = fmaf(acc[i][j][reg], arj[j], pr);
                }
                #pragma unroll
                for (int m = 1; m < 16; m <<= 1) {
                    pl += __shfl_xor(pl, m, 64);
                    pr += __shfl_xor(pr, m, 64);
                }
                if (l16 == 0 && row < M) {
                    elp[(size_t)row * HH + head] = pl;
                    erp[(size_t)row * HH + head] = pr;
                }
            }
        }
    }
}

// ---------------- fused softmax + aggregation (r4-proven config, frozen) ----------
// Sits on the ~3.2 TB/s L2-miss-path plateau (6.7 TB/s logical); lives off
// occupancy (VGPR 36, ~58%). Do not touch (r5/r6 regressions documented).
__global__ __launch_bounds__(256) void aggregate_fused(
    const ushort* __restrict__ feat16, const float* __restrict__ el,
    const float* __restrict__ er, const int* __restrict__ row_ptr,
    const int* __restrict__ csr_src, const float* __restrict__ bias,
    ushort* __restrict__ hout, int relu) {
    int wv = threadIdx.x >> 6, lane = threadIdx.x & 63;
    int node = blockIdx.x * 4 + wv;
    if (node >= NN) return;
    int c0 = lane * 4;
    int h = lane >> 4;
    float t0 = 0.f, t1 = 0.f, t2 = 0.f, t3 = 0.f;
    #pragma unroll
    for (int r = 0; r < RR; r++) {
        const int* rp = row_ptr + r * (NN + 1);
        int beg = rp[node], end = rp[node + 1];
        const ushort* fr = feat16 + (size_t)r * NN * CDIM;
        const float* elr = el + (size_t)r * NN * HH;
        float ern = er[((size_t)r * NN + node) * HH + h];
        const int* cs = csr_src + (size_t)r * EE;
        float p0 = 0.f, p1 = 0.f, p2 = 0.f, p3 = 0.f, ssum = 0.f;
        int e = beg;
        for (; e + 4 <= end; e += 4) {
            int s0 = cs[e], s1 = cs[e + 1], s2 = cs[e + 2], s3 = cs[e + 3];
            float x0 = elr[s0 * HH + h];
            float x1 = elr[s1 * HH + h];
            float x2 = elr[s2 * HH + h];
            float x3 = elr[s3 * HH + h];
            uint2 f0 = *(const uint2*)(fr + (size_t)s0 * CDIM + c0);
            uint2 f1 = *(const uint2*)(fr + (size_t)s1 * CDIM + c0);
            uint2 f2 = *(const uint2*)(fr + (size_t)s2 * CDIM + c0);
            uint2 f3 = *(const uint2*)(fr + (size_t)s3 * CDIM + c0);
            x0 += ern; x1 += ern; x2 += ern; x3 += ern;
            x0 = x0 > 0.f ? x0 : NEG * x0;
            x1 = x1 > 0.f ? x1 : NEG * x1;
            x2 = x2 > 0.f ? x2 : NEG * x2;
            x3 = x3 > 0.f ? x3 : NEG * x3;
            float a0 = __expf(x0), a1 = __expf(x1), a2 = __expf(x2), a3 = __expf(x3);
            ssum += a0 + a1 + a2 + a3;
            p0 = fmaf(a0, bflo(f0.x), p0); p1 = fmaf(a0, bfhi(f0.x), p1);
            p2 = fmaf(a0, bflo(f0.y), p2); p3 = fmaf(a0, bfhi(f0.y), p3);
            p0 = fmaf(a1, bflo(f1.x), p0); p1 = fmaf(a1, bfhi(f1.x), p1);
            p2 = fmaf(a1, bflo(f1.y), p2); p3 = fmaf(a1, bfhi(f1.y), p3);
            p0 = fmaf(a2, bflo(f2.x), p0); p1 = fmaf(a2, bfhi(f2.x), p1);
            p2 = fmaf(a2, bflo(f2.y), p2); p3 = fmaf(a2, bfhi(f2.y), p3);
            p0 = fmaf(a3, bflo(f3.x), p0); p1 = fmaf(a3, bfhi(f3.x), p1);
            p2 = fmaf(a3, bflo(f3.y), p2); p3 = fmaf(a3, bfhi(f3.y), p3);
        }
        for (; e < end; e++) {
            int s = cs[e];
            float x = elr[s * HH + h] + ern;
            x = x > 0.f ? x : NEG * x;
            float a = __expf(x);
            uint2 f = *(const uint2*)(fr + (size_t)s * CDIM + c0);
            ssum += a;
            p0 = fmaf(a, bflo(f.x), p0); p1 = fmaf(a, bfhi(f.x), p1);
            p2 = fmaf(a, bflo(f.y), p2); p3 = fmaf(a, bfhi(f.y), p3);
        }
        float is = (end > beg) ? 1.f / ssum : 0.f;
        t0 += p0 * is + bias[r * CDIM + c0];
        t1 += p1 * is + bias[r * CDIM + c0 + 1];
        t2 += p2 * is + bias[r * CDIM + c0 + 2];
        t3 += p3 * is + bias[r * CDIM + c0 + 3];
    }
    if (relu) {
        t0 = fmaxf(t0, 0.f); t1 = fmaxf(t1, 0.f);
        t2 = fmaxf(t2, 0.f); t3 = fmaxf(t3, 0.f);
    }
    uint2 o;
    o.x = (uint)f2bf(t0) | ((uint)f2bf(t1) << 16);
    o.y = (uint)f2bf(t2) | ((uint)f2bf(t3) << 16);
    *(uint2*)(hout + (size_t)node * CDIM + c0) = o;
}

// ---------------- launcher ----------------

extern "C" void kernel_launch(void* const* d_in, const int* in_sizes, int n_in,
                              void* d_out, int out_size, void* d_ws, size_t ws_size,
                              hipStream_t stream) {
    const float* x        = (const float*)d_in[0];
    const int*   edge_src = (const int*)d_in[1];
    const int*   edge_dst = (const int*)d_in[2];
    const float* W        = (const float*)d_in[3];
    const float* attn_l   = (const float*)d_in[4];
    const float* attn_r   = (const float*)d_in[5];
    const float* bias     = (const float*)d_in[6];
    const float* fc_w     = (const float*)d_in[7];
    const float* fc_b     = (const float*)d_in[8];
    float* out = (float*)d_out;

    char* ws = (char*)d_ws;
    size_t off = 0;
    auto alloc = [&](size_t bytes) {
        void* p = ws + off;
        off = (off + bytes + 255) & ~(size_t)255;
        return p;
    };
    ushort* x16    = (ushort*)alloc((size_t)NN_PAD * CDIM * 2);  // padded: glds A-source
    ushort* h16    = (ushort*)alloc((size_t)NN_PAD * CDIM * 2);  // padded: glds A-source
    ushort* feat16 = (ushort*)alloc((size_t)RR * NN * CDIM * 2);
    ushort* Wt16   = (ushort*)alloc((size_t)LL * RR * CDIM * CDIM * 2);
    ushort* fct16  = (ushort*)alloc((size_t)OUTD * CDIM * 2);
    float* el      = (float*)alloc((size_t)RR * NN * HH * 4);
    float* er      = (float*)alloc((size_t)RR * NN * HH * 4);
    int* row_ptr   = (int*)alloc((size_t)RR * (NN + 1) * 4);
    int* cursor    = (int*)alloc((size_t)RR * (NN + 1) * 4);
    int* csr_src   = (int*)alloc((size_t)RR * EE * 4);
    int* deg       = (int*)alloc((size_t)RR * NN * 4);

    // CSR build + dtype prep: memset, fused(cvt|transpose|count), scan, fill
    hipMemsetAsync(deg, 0, (size_t)RR * NN * 4, stream);
    prep_fused<<<dim3(PREP_NB), dim3(256), 0, stream>>>(
        x, W, fc_w, edge_dst, x16, Wt16, fct16, deg);
    scan_kernel<<<dim3(RR), dim3(1024), 0, stream>>>(deg, row_ptr, cursor);
    fill_csr<<<dim3((RR * EE + 255) / 256), dim3(256), 0, stream>>>(
        edge_src, edge_dst, cursor, csr_src);

    const ushort* hin = x16;
    for (int l = 0; l < LL; l++) {
        const ushort* Wl = Wt16 + (size_t)l * RR * CDIM * CDIM;
        dim3 g(NN_PAD / TM, CDIM / TN, RR);
        gemm_bf16<<<g, dim3(256), 0, stream>>>(hin, Wl, feat16, NN, CDIM, CDIM,
                                               (long)CDIM * CDIM, (long)NN * CDIM, nullptr, 0,
                                               attn_l + (size_t)l * RR * CDIM,
                                               attn_r + (size_t)l * RR * CDIM, el, er);
        aggregate_fused<<<dim3(NN / 4), dim3(256), 0, stream>>>(
            feat16, el, er, row_ptr, csr_src, bias + (size_t)l * RR * CDIM,
            h16, (l != LL - 1) ? 1 : 0);
        hin = h16;
    }
    dim3 gf(NN_PAD / TM, OUTD / TN, 1);
    gemm_bf16<<<gf, dim3(256), 0, stream>>>(h16, fct16, out, NN, CDIM, OUTD,
                                            0, 0, fc_b, 1, nullptr, nullptr, nullptr, nullptr);
}